// Round 2
// baseline (1144.283 us; speedup 1.0000x reference)
//
#include <hip/hip_runtime.h>
#include <hip/hip_bf16.h>
#include <cstddef>

#define N_NODES 100000
#define N_EDGES 600000
#define DD 128
#define LL 3
#define CC 40
#define BN_EPS 1e-5f

// dtype-adaptive load/store: f32!=0 -> buffer holds float32, else bfloat16.
__device__ __forceinline__ float ldf(const void* p, long i, int f32) {
    return f32 ? ((const float*)p)[i] : __bfloat162float(((const __hip_bfloat16*)p)[i]);
}
__device__ __forceinline__ void stf(void* p, long i, float v, int f32) {
    if (f32) ((float*)p)[i] = v;
    else     ((__hip_bfloat16*)p)[i] = __float2bfloat16(v);
}

// ---------------- dtype detection ----------------
// Interpret first 4096 elements of x as bf16. Genuine bf16 N(0,1) data -> ~0
// "bad" values. fp32 data read as bf16 -> odd elements are mantissa garbage
// (~25-45% bad: NaN / huge / tiny-denormal). Flag=1 means "inputs are fp32".
__global__ __launch_bounds__(256) void k_detect(const void* __restrict__ x, int* __restrict__ dflag) {
    __shared__ int s[256];
    int t = threadIdx.x;
    const __hip_bfloat16* xb = (const __hip_bfloat16*)x;
    int bad = 0;
    for (int i = t; i < 4096; i += 256) {
        float v = __bfloat162float(xb[i]);
        float a = fabsf(v);
        if (!(a < 1e6f)) bad++;                       // NaN or huge
        else if (v != 0.f && a < 1e-30f) bad++;       // absurdly tiny
    }
    s[t] = bad; __syncthreads();
    for (int off = 128; off > 0; off >>= 1) {
        if (t < off) s[t] += s[t + off];
        __syncthreads();
    }
    if (t == 0) *dflag = (s[0] > 64) ? 1 : 0;
}

// ---------------- graph preprocessing ----------------

__global__ __launch_bounds__(256) void k_init(int* cnt, int* fpos, int* rowptr, float* stats) {
    int i = blockIdx.x * 256 + threadIdx.x;
    if (i < N_NODES) { cnt[i] = 0; fpos[i] = 0; }
    if (i < 6 * DD) stats[i] = 0.f;
    if (i == 0) rowptr[N_NODES] = N_EDGES;
}

__global__ __launch_bounds__(256) void k_count(const int* __restrict__ ei, int* __restrict__ cnt) {
    int e = blockIdx.x * 256 + threadIdx.x;
    if (e < N_EDGES) atomicAdd(&cnt[ei[N_EDGES + e]], 1);  // dst row
}

__global__ __launch_bounds__(256) void k_scan1(const int* __restrict__ cnt, int* __restrict__ rowptr,
                                               int* __restrict__ bsum, float* __restrict__ dinv) {
    __shared__ int s[256];
    int t = threadIdx.x;
    int i = blockIdx.x * 256 + t;
    int v = (i < N_NODES) ? cnt[i] : 0;
    if (i < N_NODES) dinv[i] = 1.f / sqrtf((float)(1 + v));  // deg >= 1 (self-loop)
    s[t] = v; __syncthreads();
    for (int off = 1; off < 256; off <<= 1) {
        int x = (t >= off) ? s[t - off] : 0;
        __syncthreads();
        s[t] += x; __syncthreads();
    }
    if (i < N_NODES) rowptr[i] = s[t] - v;          // block-local exclusive
    if (t == 255) bsum[blockIdx.x] = s[255];
}

__global__ __launch_bounds__(512) void k_scan2(int* bsum, int nb) {
    __shared__ int s[512];
    int t = threadIdx.x;
    int v = (t < nb) ? bsum[t] : 0;
    s[t] = v; __syncthreads();
    for (int off = 1; off < 512; off <<= 1) {
        int x = (t >= off) ? s[t - off] : 0;
        __syncthreads();
        s[t] += x; __syncthreads();
    }
    if (t < nb) bsum[t] = s[t] - v;                 // exclusive
}

__global__ __launch_bounds__(256) void k_scan3(int* rowptr, const int* __restrict__ bsum) {
    int i = blockIdx.x * 256 + threadIdx.x;
    if (i < N_NODES) rowptr[i] += bsum[blockIdx.x];
}

__global__ __launch_bounds__(256) void k_fill(const int* __restrict__ ei, int* __restrict__ fpos,
                                              const int* __restrict__ rowptr, int* __restrict__ adj) {
    int e = blockIdx.x * 256 + threadIdx.x;
    if (e < N_EDGES) {
        int d = ei[N_EDGES + e];
        int p = atomicAdd(&fpos[d], 1);
        adj[rowptr[d] + p] = ei[e];                 // src
    }
}

__global__ __launch_bounds__(256) void k_cvt(const void* __restrict__ x, float* __restrict__ o,
                                             const int* __restrict__ dflag) {
    int f = *dflag;
    int i = blockIdx.x * 256 + threadIdx.x;         // grid covers exactly N*DD
    o[i] = ldf(x, i, f);
}

// ---- fp32 GEMM: C[nrows x 128] = A[nrows x 128] * W[128 x 128] (+bias, relu) ----

__global__ __launch_bounds__(256) void k_gemm(const float* __restrict__ A, const void* __restrict__ W,
                                              long woff, const void* __restrict__ bias,
                                              float* __restrict__ Cout, int nrows, int relu,
                                              const int* __restrict__ dflag) {
    __shared__ float Alds[32][68];    // [k][row], 68*4=272B row stride stays 16B aligned
    __shared__ float Wlds[32][128];   // [k][col]
    int f = *dflag;
    int tid = threadIdx.x;
    int rowbase = blockIdx.x * 64;
    int tx = tid & 31;                // cols tx*4 .. tx*4+3
    int ty = tid >> 5;                // rows ty*8 .. ty*8+7
    float acc[8][4];
    #pragma unroll
    for (int i = 0; i < 8; ++i)
        #pragma unroll
        for (int j = 0; j < 4; ++j) acc[i][j] = 0.f;

    for (int kt = 0; kt < 128; kt += 32) {
        #pragma unroll
        for (int u = tid; u < 64 * 32; u += 256) {
            int a = u >> 5, k = u & 31;
            int r = rowbase + a;
            Alds[k][a] = (r < nrows) ? A[(long)r * 128 + kt + k] : 0.f;
        }
        #pragma unroll
        for (int u = tid; u < 32 * 128; u += 256) {
            int k = u >> 7, c = u & 127;
            Wlds[k][c] = ldf(W, woff + (long)(kt + k) * 128 + c, f);
        }
        __syncthreads();
        #pragma unroll
        for (int k = 0; k < 32; ++k) {
            float4 a0 = *(const float4*)&Alds[k][ty * 8];
            float4 a1 = *(const float4*)&Alds[k][ty * 8 + 4];
            float4 wv = *(const float4*)&Wlds[k][tx * 4];
            float av[8] = {a0.x, a0.y, a0.z, a0.w, a1.x, a1.y, a1.z, a1.w};
            float wj[4] = {wv.x, wv.y, wv.z, wv.w};
            #pragma unroll
            for (int i = 0; i < 8; ++i)
                #pragma unroll
                for (int j = 0; j < 4; ++j) acc[i][j] += av[i] * wj[j];
        }
        __syncthreads();
    }
    #pragma unroll
    for (int i = 0; i < 8; ++i) {
        int r = rowbase + ty * 8 + i;
        if (r < nrows) {
            #pragma unroll
            for (int j = 0; j < 4; ++j) {
                int c = tx * 4 + j;
                float v = acc[i][j];
                if (bias) v += ldf(bias, c, f);
                if (relu) v = fmaxf(v, 0.f);
                Cout[(long)r * 128 + c] = v;
            }
        }
    }
}

// ---- CSR aggregation: out_i = dinv_i*(dinv_i*XW_i + sum_j dinv_j*XW_j) + b ----

__global__ __launch_bounds__(256) void k_agg(const float* __restrict__ XW, const int* __restrict__ rowptr,
                                             const int* __restrict__ adj, const float* __restrict__ dinv,
                                             const void* __restrict__ bias, long boff,
                                             float* __restrict__ outp, const int* __restrict__ dflag) {
    int f = *dflag;
    int wave = threadIdx.x >> 6;
    int lane = threadIdx.x & 63;
    int i = blockIdx.x * 4 + wave;
    if (i >= N_NODES) return;
    const float2* XW2 = (const float2*)XW;
    float di = dinv[i];
    int e0 = rowptr[i], e1 = rowptr[i + 1];
    float2 self = XW2[(size_t)i * 64 + lane];
    float acc0 = di * self.x, acc1 = di * self.y;
    for (int e = e0; e < e1; ++e) {
        int j = adj[e];
        float dj = dinv[j];
        float2 v = XW2[(size_t)j * 64 + lane];
        acc0 += dj * v.x;
        acc1 += dj * v.y;
    }
    float2 r;
    r.x = di * acc0 + ldf(bias, boff + 2 * lane, f);
    r.y = di * acc1 + ldf(bias, boff + 2 * lane + 1, f);
    ((float2*)outp)[(size_t)i * 64 + lane] = r;
}

// ---------------- BatchNorm (batch stats) + PReLU ----------------

__global__ __launch_bounds__(256) void k_bn_reduce(const float* __restrict__ H, float* __restrict__ sums,
                                                   float* __restrict__ sumsq) {
    int c = threadIdx.x & 127;
    int half = threadIdx.x >> 7;
    float s = 0.f, q = 0.f;
    for (int r = blockIdx.x * 2 + half; r < N_NODES; r += gridDim.x * 2) {
        float v = H[(long)r * 128 + c];
        s += v; q += v * v;
    }
    __shared__ float ls[256], lq[256];
    ls[threadIdx.x] = s; lq[threadIdx.x] = q;
    __syncthreads();
    if (threadIdx.x < 128) {
        atomicAdd(&sums[c], ls[threadIdx.x] + ls[threadIdx.x + 128]);
        atomicAdd(&sumsq[c], lq[threadIdx.x] + lq[threadIdx.x + 128]);
    }
}

__global__ __launch_bounds__(256) void k_bn_apply(float* __restrict__ H, const float* __restrict__ sums,
                                                  const float* __restrict__ sumsq,
                                                  const void* __restrict__ g, const void* __restrict__ b,
                                                  const void* __restrict__ a, int l,
                                                  void* __restrict__ emb_out,
                                                  const int* __restrict__ dflag) {
    int f = *dflag;
    int idx = blockIdx.x * 256 + threadIdx.x;       // grid covers exactly N*DD
    int c = idx & 127;
    float mean = sums[c] / (float)N_NODES;
    float var = sumsq[c] / (float)N_NODES - mean * mean;
    float inv = 1.f / sqrtf(var + BN_EPS);
    float ga = ldf(g, (long)l * DD + c, f);
    float be = ldf(b, (long)l * DD + c, f);
    float al = ldf(a, l, f);
    float v = H[idx];
    float y = (v - mean) * inv * ga + be;
    y = (y > 0.f) ? y : al * y;
    H[idx] = y;
    if (emb_out) stf(emb_out, idx, y, f);
}

// ---- head: logits = hidden @ Wh2 + bh2 ; argmax (first-max tie-break) ----

__global__ __launch_bounds__(256) void k_head(const float* __restrict__ Hd, const void* __restrict__ W2,
                                              const void* __restrict__ b2,
                                              void* __restrict__ out_base,   // element offsets into d_out
                                              const int* __restrict__ dflag) {
    __shared__ float Wl[128][40];
    __shared__ float bl[40];
    __shared__ float rv[32][8];
    __shared__ int ri[32][8];
    int f = *dflag;
    int tid = threadIdx.x;
    for (int u = tid; u < 128 * 40; u += 256) Wl[u / 40][u % 40] = ldf(W2, u, f);
    if (tid < 40) bl[tid] = ldf(b2, tid, f);
    __syncthreads();
    int rl = tid >> 3, g = tid & 7;
    long r = (long)blockIdx.x * 32 + rl;            // 3125*32 == N exactly
    float acc[5];
    #pragma unroll
    for (int j = 0; j < 5; ++j) acc[j] = bl[g * 5 + j];
    for (int k = 0; k < 128; ++k) {
        float h = Hd[r * 128 + k];
        #pragma unroll
        for (int j = 0; j < 5; ++j) acc[j] += h * Wl[k][g * 5 + j];
    }
    float best = acc[0]; int bi = 0;
    #pragma unroll
    for (int j = 1; j < 5; ++j)
        if (acc[j] > best) { best = acc[j]; bi = j; }   // strictly > keeps first max
    const long LOG_OFF = (long)N_NODES * DD;
    const long ARG_OFF = (long)N_NODES * (DD + CC);
    #pragma unroll
    for (int j = 0; j < 5; ++j) stf(out_base, LOG_OFF + r * 40 + g * 5 + j, acc[j], f);
    rv[rl][g] = best; ri[rl][g] = g * 5 + bi;
    __syncthreads();
    if (tid < 32) {
        long row = (long)blockIdx.x * 32 + tid;
        float bb = rv[tid][0]; int bbi = ri[tid][0];
        #pragma unroll
        for (int g2 = 1; g2 < 8; ++g2)
            if (rv[tid][g2] > bb) { bb = rv[tid][g2]; bbi = ri[tid][g2]; }  // ascending, strictly >
        stf(out_base, ARG_OFF + row, (float)bbi, f);
    }
}

// ---------------- launch ----------------

extern "C" void kernel_launch(void* const* d_in, const int* in_sizes, int n_in,
                              void* d_out, int out_size, void* d_ws, size_t ws_size,
                              hipStream_t stream) {
    const void* x   = d_in[0];
    const int* ei   = (const int*)d_in[1];
    const void* Ws  = d_in[2];
    const void* bs  = d_in[3];
    const void* gam = d_in[4];
    const void* bet = d_in[5];
    const void* pa  = d_in[6];
    const void* Wh1 = d_in[7];
    const void* bh1 = d_in[8];
    const void* Wh2 = d_in[9];
    const void* bh2 = d_in[10];

    char* w = (char*)d_ws;
    int* cnt     = (int*)w;    w += sizeof(int) * N_NODES;
    int* fpos    = (int*)w;    w += sizeof(int) * N_NODES;
    int* rowptr  = (int*)w;    w += sizeof(int) * (N_NODES + 4);
    int* adj     = (int*)w;    w += sizeof(int) * N_EDGES;
    int* bsum    = (int*)w;    w += sizeof(int) * 512;
    int* dflag   = (int*)w;    w += sizeof(int) * 4;
    float* dinv  = (float*)w;  w += sizeof(float) * N_NODES;
    float* stats = (float*)w;  w += sizeof(float) * (6 * DD);
    float* bufA  = (float*)w;  w += sizeof(float) * (size_t)N_NODES * DD;
    float* bufB  = (float*)w;  w += sizeof(float) * (size_t)N_NODES * DD;

    const int scanBlocks = (N_NODES + 255) / 256;       // 391
    const int edgeBlocks = (N_EDGES + 255) / 256;       // 2344
    const int elemBlocks = (N_NODES * DD) / 256;        // 50000 exact
    const int gemmBlocks = (N_NODES + 63) / 64;         // 1563

    k_detect<<<1, 256, 0, stream>>>(x, dflag);
    k_init<<<scanBlocks, 256, 0, stream>>>(cnt, fpos, rowptr, stats);
    k_count<<<edgeBlocks, 256, 0, stream>>>(ei, cnt);
    k_scan1<<<scanBlocks, 256, 0, stream>>>(cnt, rowptr, bsum, dinv);
    k_scan2<<<1, 512, 0, stream>>>(bsum, scanBlocks);
    k_scan3<<<scanBlocks, 256, 0, stream>>>(rowptr, bsum);
    k_fill<<<edgeBlocks, 256, 0, stream>>>(ei, fpos, rowptr, adj);
    k_cvt<<<elemBlocks, 256, 0, stream>>>(x, bufA, dflag);

    for (int l = 0; l < LL; ++l) {
        k_gemm<<<gemmBlocks, 256, 0, stream>>>(bufA, Ws, (long)l * DD * DD, nullptr, bufB,
                                               N_NODES, 0, dflag);
        k_agg<<<(N_NODES + 3) / 4, 256, 0, stream>>>(bufB, rowptr, adj, dinv, bs, (long)l * DD,
                                                     bufA, dflag);
        k_bn_reduce<<<256, 256, 0, stream>>>(bufA, stats + l * 2 * DD, stats + l * 2 * DD + DD);
        k_bn_apply<<<elemBlocks, 256, 0, stream>>>(bufA, stats + l * 2 * DD, stats + l * 2 * DD + DD,
                                                   gam, bet, pa, l,
                                                   (l == LL - 1) ? d_out : nullptr, dflag);
    }

    k_gemm<<<gemmBlocks, 256, 0, stream>>>(bufA, Wh1, 0, bh1, bufB, N_NODES, 1, dflag);
    k_head<<<(N_NODES / 32), 256, 0, stream>>>(bufB, Wh2, bh2, d_out, dflag);
}